// Round 10
// baseline (1188.692 us; speedup 1.0000x reference)
//
#include <hip/hip_runtime.h>
#include <stdint.h>

#define T_TOK   16384
#define D_INK   2048
#define D_OUTN  8192
#define G_NUM   8

#define BM 256
#define BN 256
#define BK 64
#define NKT (D_INK / BK)        // 32 K-tiles (even -> clean 2-tile supersteps)
#define MT_TILES (T_TOK / BM)   // 64
#define NT_TILES (D_OUTN / BN)  // 32
#define MCHUNK 4                // m-tiles per L2 chunk (R4 ordering, best measured)

typedef __attribute__((ext_vector_type(8))) short bf16x8;
typedef __attribute__((ext_vector_type(4))) float f32x4;

#define BARRIER() do { asm volatile("" ::: "memory"); __builtin_amdgcn_s_barrier(); asm volatile("" ::: "memory"); } while (0)
#define VMCNT(n)  asm volatile("s_waitcnt vmcnt(" #n ")" ::: "memory")
// operand-swapped: D = W_frag x X_frag -> D.lane&15 = token row, reg-axis = output col
#define MFMA16(d,vw,vx) d = __builtin_amdgcn_mfma_f32_16x16x32_bf16(vw, vx, d, 0, 0, 0)

// ---------- fp32 -> bf16 (RNE) conversion, vectorized ----------
__device__ __forceinline__ unsigned int f2bf(float f) {
    union { float f; unsigned int u; } v; v.f = f;
    unsigned int u = v.u;
    unsigned int r = u + 0x7FFFu + ((u >> 16) & 1u);
    return r >> 16;
}

__global__ __launch_bounds__(256) void cvt_f32_bf16(const float* __restrict__ src,
                                                    unsigned short* __restrict__ dst,
                                                    long long n8) {
    long long i = (long long)blockIdx.x * blockDim.x + threadIdx.x;
    long long stride = (long long)gridDim.x * blockDim.x;
    const float4* s4 = reinterpret_cast<const float4*>(src);
    for (; i < n8; i += stride) {
        float4 x = s4[i * 2];
        float4 y = s4[i * 2 + 1];
        uint4 o;
        o.x = f2bf(x.x) | (f2bf(x.y) << 16);
        o.y = f2bf(x.z) | (f2bf(x.w) << 16);
        o.z = f2bf(y.x) | (f2bf(y.y) << 16);
        o.w = f2bf(y.z) | (f2bf(y.w) << 16);
        *reinterpret_cast<uint4*>(dst + i * 8) = o;
    }
}

// ---------- async global->LDS, 16B per lane ----------
__device__ __forceinline__ void gload_lds16(const unsigned short* g, void* l) {
    __builtin_amdgcn_global_load_lds(
        (const __attribute__((address_space(1))) void*)g,
        (__attribute__((address_space(3))) void*)l,
        16, 0, 0);
}

// ---------- 256x256 8-phase grouped GEMM: C[t,o] = sum_k A[t,k] * W[g][o,k] ----------
// LDS per operand tile [256 rows][64 k]: 32 subtiles of 16x32 bf16 (1024 B),
// st_16x32 swizzle (measured R2-R8: SQ_LDS_BANK_CONFLICT == 0); gload_lds writes
// linearly, swizzle inverse folded into per-lane GLOBAL address (rule #21).
// Schedule: R4's 2-K-tile superstep, 8 phases, one half-tile stage per phase,
// vmcnt(4) twice per superstep (never 0 mid-loop), in-phase fragment reads with
// compiler counted-lgkm. Decomposition (4m x 4n x 1ks): reads/phase {8,4,8,4}.
// R9 LESSON (rule #20): fragment arrays are accessed ONLY as captured arrays
// with literal indices -- never passed as pointers -- so they stay in VGPRs
// (R9's pointer-passing sent them to scratch: +90MB FETCH/+93MB WRITE, 2x slower).
__global__ __launch_bounds__(512, 2) void grouped_gemm_256(
    const unsigned short* __restrict__ Abf,   // [T_TOK][D_INK] bf16
    const unsigned short* __restrict__ Wbf,   // [G][D_OUTN][D_INK] bf16
    const int* __restrict__ offs_raw,         // cumsum ends; int32 or int64-in-memory
    float* __restrict__ out)                  // [T_TOK][D_OUTN] fp32
{
    __shared__ unsigned short lds[2][32768];  // 2 dbuf x (A 32KB + B 32KB) = 128 KiB

    const int tid  = threadIdx.x;
    const int wave = tid >> 6;
    const int lane = tid & 63;

    // T1: XCD-bijective swizzle (nwg=2048 % 8 == 0) + MCHUNK chunk order (R4)
    const int swz = (blockIdx.x & 7) * (MT_TILES * NT_TILES / 8) + (blockIdx.x >> 3);
    const int per_chunk = MCHUNK * NT_TILES;          // 128
    const int chunk = swz / per_chunk;
    const int rem   = swz % per_chunk;
    const int nt = rem >> 2;                          // rem / MCHUNK
    const int mt = chunk * MCHUNK + (rem & (MCHUNK - 1));

    const int row0 = mt * BM;
    const int col0 = nt * BN;

    // group id (offsets int32, or int64 whose high words read as 0);
    // all group boundaries are multiples of 256 -> tiles never straddle.
    const int ostride = (offs_raw[1] == 0) ? 2 : 1;
    int g = 0;
#pragma unroll
    for (int i = 0; i < G_NUM - 1; ++i)
        if (row0 >= offs_raw[i * ostride]) g = i + 1;

    const unsigned short* Aorig = Abf + (size_t)row0 * D_INK;
    const unsigned short* Worig = Wbf + ((size_t)g * D_OUTN + col0) * D_INK;

    // staging lane geometry: within a subtile, lane l covers logical row l>>2,
    // cols ((l&3)*8) ^ ((l&32)?16:0) .. +8  (inverse st_16x32 swizzle on source)
    const int lrow = lane >> 2;
    const int gcol_off = ((lane & 3) * 8) ^ ((lane & 32) ? 16 : 0);

    // fragment-read lane geometry (mfma 16x16x32 bf16)
    const int fr  = lane & 15;
    const int fk2 = (lane >> 4) << 4;
    const int swz_off = fr * 64 + (fk2 ^ ((fr & 8) ? 32 : 0));
    const int wm16 = (wave >> 2) * 8;          // A subtile-row base (wave: 128 rows)
    const int wn16 = (wave & 3) * 4;           // B subtile-row base (wave: 64 rows)
    const int wm = (wave >> 2) * 128;
    const int wn = (wave & 3) * 64;

    char* ldsc = (char*)&lds[0][0];

    // stage one HALF-tile (128 rows x 64 k = 16 KB = 2 insts/thread)
    auto stageAh = [&](int buf, int kt, int h) {
#pragma unroll
        for (int i = 0; i < 2; ++i) {
            const int s = h * 16 + i * 8 + wave;
            const int sr = s >> 1, sc = s & 1;
            const unsigned short* src = Aorig + (size_t)(sr * 16 + lrow) * D_INK
                                        + kt * BK + sc * 32 + gcol_off;
            gload_lds16(src, ldsc + buf * 65536 + s * 1024);
        }
    };
    auto stageBh = [&](int buf, int kt, int h) {
#pragma unroll
        for (int i = 0; i < 2; ++i) {
            const int s = h * 16 + i * 8 + wave;
            const int sr = s >> 1, sc = s & 1;
            const unsigned short* src = Worig + (size_t)(sr * 16 + lrow) * D_INK
                                        + kt * BK + sc * 32 + gcol_off;
            gload_lds16(src, ldsc + buf * 65536 + 32768 + s * 1024);
        }
    };

    f32x4 acc[8][4] = {};
    bf16x8 a[4], a2[4], b[4];   // captured arrays, literal-index access only

    // single-ks fragment reads; all writes/reads via captured arrays, unrolled
    auto ldB4 = [&](int buf, int ks) {
#pragma unroll
        for (int j = 0; j < 4; ++j)
            b[j] = *reinterpret_cast<const bf16x8*>(
                ldsc + buf * 65536 + 32768 + ((wn16 + j) * 2 + ks) * 1024 + swz_off);
    };
    auto ldA4lo = [&](int buf, int ks) {
#pragma unroll
        for (int i = 0; i < 4; ++i)
            a[i] = *reinterpret_cast<const bf16x8*>(
                ldsc + buf * 65536 + ((wm16 + i) * 2 + ks) * 1024 + swz_off);
    };
    auto ldA4hi = [&](int buf, int ks) {
#pragma unroll
        for (int i = 0; i < 4; ++i)
            a2[i] = *reinterpret_cast<const bf16x8*>(
                ldsc + buf * 65536 + ((wm16 + 4 + i) * 2 + ks) * 1024 + swz_off);
    };
    // 16 MFMA: 4 m-frags (a) x 4 n-frags x 1 k-slice, acc rows 0-3
    auto quadLo = [&]() {
        __builtin_amdgcn_s_setprio(1);
#pragma unroll
        for (int i = 0; i < 4; ++i)
#pragma unroll
            for (int j = 0; j < 4; ++j)
                MFMA16(acc[i][j], b[j], a[i]);
        __builtin_amdgcn_s_setprio(0);
    };
    // 16 MFMA: 4 m-frags (a2) x 4 n-frags x 1 k-slice, acc rows 4-7
    auto quadHi = [&]() {
        __builtin_amdgcn_s_setprio(1);
#pragma unroll
        for (int i = 0; i < 4; ++i)
#pragma unroll
            for (int j = 0; j < 4; ++j)
                MFMA16(acc[4 + i][j], b[j], a2[i]);
        __builtin_amdgcn_s_setprio(0);
    };

    // prologue: tile0 (B then A) + B(1) = 12 insts; vmcnt(4) -> tile0 landed,
    // B(1) (4 insts) stays in flight == steady-state superstep entry condition.
    stageBh(0, 0, 0); stageBh(0, 0, 1);
    stageAh(0, 0, 0); stageAh(0, 0, 1);
    stageBh(1, 1, 0); stageBh(1, 1, 1);
    VMCNT(4);
    BARRIER();

    for (int t = 0; t < NKT; t += 2) {
        const bool s2 = (t + 2 < NKT), s3 = (t + 3 < NKT);

        // ---- tile t (buf0) ----
        // ph0: ks0, b0-3 + a0-3 (8 reads); stage A(t+1) half0 -> buf1
        ldB4(0, 0); ldA4lo(0, 0);
        stageAh(1, t + 1, 0);
        BARRIER(); quadLo(); BARRIER();

        // ph1: ks0, a4-7 (4 reads, b reused); stage A(t+1) half1
        ldA4hi(0, 0);
        stageAh(1, t + 1, 1);
        BARRIER(); quadHi(); BARRIER();

        // ph2: ks1, b0-3 + a0-3 (8 reads); stage B(t+2) half0 -> buf0
        ldB4(0, 1); ldA4lo(0, 1);
        if (s2) stageBh(0, t + 2, 0);
        BARRIER(); quadLo(); BARRIER();

        // ph3: ks1, a4-7 (4 reads); stage B(t+2) half1;
        // vmcnt(4): waits B(t+1)+A(t+1) landed, leaves B(t+2) in flight.
        ldA4hi(0, 1);
        if (s2) stageBh(0, t + 2, 1);
        BARRIER();
        quadHi();
        if (s2) { VMCNT(4); } else { VMCNT(0); }
        BARRIER();

        // ---- tile t+1 (buf1) ----
        // ph4: ks0; stage A(t+2) half0 -> buf0
        ldB4(1, 0); ldA4lo(1, 0);
        if (s2) stageAh(0, t + 2, 0);
        BARRIER(); quadLo(); BARRIER();

        // ph5: ks0, a4-7; stage A(t+2) half1
        ldA4hi(1, 0);
        if (s2) stageAh(0, t + 2, 1);
        BARRIER(); quadHi(); BARRIER();

        // ph6: ks1; stage B(t+3) half0 -> buf1
        ldB4(1, 1); ldA4lo(1, 1);
        if (s3) stageBh(1, t + 3, 0);
        BARRIER(); quadLo(); BARRIER();

        // ph7: ks1, a4-7; stage B(t+3) half1;
        // vmcnt(4): waits B(t+2)+A(t+2) landed, leaves B(t+3) in flight.
        ldA4hi(1, 1);
        if (s3) stageBh(1, t + 3, 1);
        BARRIER();
        quadHi();
        if (s3) { VMCNT(4); } else { VMCNT(0); }
        BARRIER();
    }

    // ---- C-write (operand-swapped layout, verified R5-R8): lane&15 = token row,
    //      (lane>>4)*4 + reg = output col -> one float4 store per (i,j).
    const int m_in   = lane & 15;
    const int n_base = (lane >> 4) * 4;
#pragma unroll
    for (int i = 0; i < 8; ++i) {
        const size_t rbase = (size_t)(row0 + wm + i * 16 + m_in) * D_OUTN;
#pragma unroll
        for (int j = 0; j < 4; ++j) {
            const int cc = col0 + wn + j * 16 + n_base;
            *reinterpret_cast<f32x4*>(&out[rbase + cc]) = acc[i][j];
        }
    }
}

// ---------- fallback (only if d_ws too small): naive fp32 ----------
__global__ __launch_bounds__(256) void naive_grouped(
    const float* __restrict__ A, const float* __restrict__ W,
    const int* __restrict__ offs_raw, float* __restrict__ out)
{
    const long long total = (long long)T_TOK * D_OUTN;
    long long idx = (long long)blockIdx.x * blockDim.x + threadIdx.x;
    const long long stride = (long long)gridDim.x * blockDim.x;
    const int ostride = (offs_raw[1] == 0) ? 2 : 1;
    for (; idx < total; idx += stride) {
        const int t = (int)(idx / D_OUTN);
        const int c = (int)(idx % D_OUTN);
        int g = 0;
        for (int i = 0; i < G_NUM - 1; ++i)
            if (t >= offs_raw[i * ostride]) g = i + 1;
        const float4* a4 = reinterpret_cast<const float4*>(A + (size_t)t * D_INK);
        const float4* w4 = reinterpret_cast<const float4*>(W + ((size_t)g * D_OUTN + c) * D_INK);
        float s = 0.f;
        for (int k = 0; k < D_INK / 4; ++k) {
            float4 av = a4[k], wv = w4[k];
            s += av.x * wv.x + av.y * wv.y + av.z * wv.z + av.w * wv.w;
        }
        out[idx] = s;
    }
}

extern "C" void kernel_launch(void* const* d_in, const int* in_sizes, int n_in,
                              void* d_out, int out_size, void* d_ws, size_t ws_size,
                              hipStream_t stream) {
    const float* hidden = (const float*)d_in[0];
    const int*   offs   = (const int*)d_in[1];
    const float* weight = (const float*)d_in[2];
    float* out = (float*)d_out;

    const size_t nA = (size_t)T_TOK * D_INK;            // 33.5M
    const size_t nW = (size_t)G_NUM * D_OUTN * D_INK;   // 134M
    const size_t need = (nA + nW) * sizeof(unsigned short);

    if (ws_size >= need) {
        unsigned short* Abf = (unsigned short*)d_ws;
        unsigned short* Wbf = Abf + nA;
        cvt_f32_bf16<<<2048, 256, 0, stream>>>(hidden, Abf, (long long)(nA / 8));
        cvt_f32_bf16<<<4096, 256, 0, stream>>>(weight, Wbf, (long long)(nW / 8));
        grouped_gemm_256<<<MT_TILES * NT_TILES, 512, 0, stream>>>(Abf, Wbf, offs, out);
    } else {
        naive_grouped<<<8192, 256, 0, stream>>>(hidden, weight, offs, out);
    }
}

// Round 11
// 706.861 us; speedup vs baseline: 1.6816x; 1.6816x over previous
//
#include <hip/hip_runtime.h>
#include <stdint.h>

#define T_TOK   16384
#define D_INK   2048
#define D_OUTN  8192
#define G_NUM   8

#define BM 256
#define BN 256
#define BK 64
#define NKT (D_INK / BK)        // 32 K-tiles (even -> clean 2-tile supersteps)
#define MT_TILES (T_TOK / BM)   // 64
#define NT_TILES (D_OUTN / BN)  // 32
#define MCHUNK 4                // m-tiles per L2 chunk (4 MB A-panel per XCD)

typedef __attribute__((ext_vector_type(8))) short bf16x8;
typedef __attribute__((ext_vector_type(4))) float f32x4;

#define BARRIER() do { asm volatile("" ::: "memory"); __builtin_amdgcn_s_barrier(); asm volatile("" ::: "memory"); } while (0)
#define VMCNT(n)  asm volatile("s_waitcnt vmcnt(" #n ")" ::: "memory")
#define MFMA16(d,va,vb) d = __builtin_amdgcn_mfma_f32_16x16x32_bf16(va, vb, d, 0, 0, 0)

// ---------- fp32 -> bf16 (RNE) conversion, vectorized ----------
__device__ __forceinline__ unsigned int f2bf(float f) {
    union { float f; unsigned int u; } v; v.f = f;
    unsigned int u = v.u;
    unsigned int r = u + 0x7FFFu + ((u >> 16) & 1u);
    return r >> 16;
}

__global__ __launch_bounds__(256) void cvt_f32_bf16(const float* __restrict__ src,
                                                    unsigned short* __restrict__ dst,
                                                    long long n8) {
    long long i = (long long)blockIdx.x * blockDim.x + threadIdx.x;
    long long stride = (long long)gridDim.x * blockDim.x;
    const float4* s4 = reinterpret_cast<const float4*>(src);
    for (; i < n8; i += stride) {
        float4 x = s4[i * 2];
        float4 y = s4[i * 2 + 1];
        uint4 o;
        o.x = f2bf(x.x) | (f2bf(x.y) << 16);
        o.y = f2bf(x.z) | (f2bf(x.w) << 16);
        o.z = f2bf(y.x) | (f2bf(y.y) << 16);
        o.w = f2bf(y.z) | (f2bf(y.w) << 16);
        *reinterpret_cast<uint4*>(dst + i * 8) = o;
    }
}

// ---------- async global->LDS, 16B per lane ----------
__device__ __forceinline__ void gload_lds16(const unsigned short* g, void* l) {
    __builtin_amdgcn_global_load_lds(
        (const __attribute__((address_space(1))) void*)g,
        (__attribute__((address_space(3))) void*)l,
        16, 0, 0);
}

// ---------- 256x256 8-phase grouped GEMM: C[t,o] = sum_k A[t,k] * W[g][o,k] ----------
// EXACT restoration of the best-measured kernel (562-572 us GEMM, 709 us total,
// MfmaUtil 44%, WRITE 537 MB, SQ_LDS_BANK_CONFLICT 0 -- measured twice).
// LDS per operand tile [256 rows][64 k]: 32 subtiles of 16x32 bf16 (1024 B),
// st_16x32 swizzle; gload_lds writes linearly, swizzle inverse folded into the
// per-lane GLOBAL address (rule #21). Schedule: 2-K-tile superstep, 8 phases;
// each phase = {quadrant ds-reads (first-consumed first), ONE half-tile stage
// (2 insts), barrier, 16 MFMA, barrier}. NO explicit lgkm drain (compiler emits
// counted lgkmcnt from register deps). vmcnt(4) twice per superstep, never 0.
__global__ __launch_bounds__(512, 2) void grouped_gemm_256(
    const unsigned short* __restrict__ Abf,   // [T_TOK][D_INK] bf16
    const unsigned short* __restrict__ Wbf,   // [G][D_OUTN][D_INK] bf16
    const int* __restrict__ offs_raw,         // cumsum ends; int32 or int64-in-memory
    float* __restrict__ out)                  // [T_TOK][D_OUTN] fp32
{
    __shared__ unsigned short lds[2][32768];  // 2 dbuf x (A 32KB + B 32KB) = 128 KiB

    const int tid  = threadIdx.x;
    const int wave = tid >> 6;
    const int lane = tid & 63;

    // T1: XCD-bijective swizzle (nwg=2048 % 8 == 0) + MCHUNK chunk order
    const int swz = (blockIdx.x & 7) * (MT_TILES * NT_TILES / 8) + (blockIdx.x >> 3);
    const int per_chunk = MCHUNK * NT_TILES;          // 128
    const int chunk = swz / per_chunk;
    const int rem   = swz % per_chunk;
    const int nt = rem >> 2;                          // rem / MCHUNK
    const int mt = chunk * MCHUNK + (rem & (MCHUNK - 1));

    const int row0 = mt * BM;
    const int col0 = nt * BN;

    // group id (offsets int32, or int64 whose high words read as 0);
    // all group boundaries are multiples of 256 -> tiles never straddle.
    const int ostride = (offs_raw[1] == 0) ? 2 : 1;
    int g = 0;
#pragma unroll
    for (int i = 0; i < G_NUM - 1; ++i)
        if (row0 >= offs_raw[i * ostride]) g = i + 1;

    const unsigned short* Aorig = Abf + (size_t)row0 * D_INK;
    const unsigned short* Worig = Wbf + ((size_t)g * D_OUTN + col0) * D_INK;

    // staging lane geometry: within a subtile, lane l covers logical row l>>2,
    // cols ((l&3)*8) ^ ((l&32)?16:0) .. +8  (inverse st_16x32 swizzle on source)
    const int lrow = lane >> 2;
    const int gcol_off = ((lane & 3) * 8) ^ ((lane & 32) ? 16 : 0);

    // fragment-read lane geometry (mfma 16x16x32 bf16)
    const int fr  = lane & 15;                 // row within fragment
    const int fk2 = (lane >> 4) << 4;          // k-byte base within 32-col subtile
    const int swz_off = fr * 64 + (fk2 ^ ((fr & 8) ? 32 : 0));
    const int wm16 = (wave >> 2) * 8;          // A subtile-row base (wave covers 128 rows)
    const int wn16 = (wave & 3) * 4;           // B subtile-row base (wave covers 64 rows)
    const int wm = (wave >> 2) * 128;
    const int wn = (wave & 3) * 64;

    char* ldsc = (char*)&lds[0][0];

    // stage one HALF-tile (128 rows x 64 k = 16 KB = 2 insts/thread)
    auto stageAh = [&](int buf, int kt, int h) {
#pragma unroll
        for (int i = 0; i < 2; ++i) {
            const int s = h * 16 + i * 8 + wave;
            const int sr = s >> 1, sc = s & 1;
            const unsigned short* src = Aorig + (size_t)(sr * 16 + lrow) * D_INK
                                        + kt * BK + sc * 32 + gcol_off;
            gload_lds16(src, ldsc + buf * 65536 + s * 1024);
        }
    };
    auto stageBh = [&](int buf, int kt, int h) {
#pragma unroll
        for (int i = 0; i < 2; ++i) {
            const int s = h * 16 + i * 8 + wave;
            const int sr = s >> 1, sc = s & 1;
            const unsigned short* src = Worig + (size_t)(sr * 16 + lrow) * D_INK
                                        + kt * BK + sc * 32 + gcol_off;
            gload_lds16(src, ldsc + buf * 65536 + 32768 + s * 1024);
        }
    };

    f32x4 acc[8][4] = {};
    bf16x8 a[4][2], b[4][2];

    // ds-read issue order inside each phase: first-consumed operands FIRST
    // (in-order lgkm queue -> compiler's counted waits release MFMA earliest).
    auto ldB2 = [&](int buf, int jb) {
#pragma unroll
        for (int j = 0; j < 2; ++j) {
            const int sr = wn16 + jb + j;
            b[jb + j][0] = *reinterpret_cast<const bf16x8*>(ldsc + buf * 65536 + 32768 + (sr * 2 + 0) * 1024 + swz_off);
            b[jb + j][1] = *reinterpret_cast<const bf16x8*>(ldsc + buf * 65536 + 32768 + (sr * 2 + 1) * 1024 + swz_off);
        }
    };
    auto ldA4 = [&](int buf, int mb) {
#pragma unroll
        for (int i = 0; i < 4; ++i) {
            const int sr = wm16 + mb + i;
            a[i][0] = *reinterpret_cast<const bf16x8*>(ldsc + buf * 65536 + (sr * 2 + 0) * 1024 + swz_off);
            a[i][1] = *reinterpret_cast<const bf16x8*>(ldsc + buf * 65536 + (sr * 2 + 1) * 1024 + swz_off);
        }
    };
    auto quad = [&](int ib, int jb) {
        __builtin_amdgcn_s_setprio(1);
#pragma unroll
        for (int i = 0; i < 4; ++i)
#pragma unroll
            for (int j = 0; j < 2; ++j) {
                MFMA16(acc[ib + i][jb + j], a[i][0], b[jb + j][0]);
                MFMA16(acc[ib + i][jb + j], a[i][1], b[jb + j][1]);
            }
        __builtin_amdgcn_s_setprio(0);
    };

    // prologue: tile0 (B then A) + B(1) = 12 insts; vmcnt(4) -> tile0 landed,
    // B(1) (4 insts) stays in flight == steady-state superstep entry condition.
    stageBh(0, 0, 0); stageBh(0, 0, 1);
    stageAh(0, 0, 0); stageAh(0, 0, 1);
    stageBh(1, 1, 0); stageBh(1, 1, 1);
    VMCNT(4);
    BARRIER();

    for (int t = 0; t < NKT; t += 2) {
        const bool s2 = (t + 2 < NKT), s3 = (t + 3 < NKT);

        // ---- tile t (buf0) ----
        // ph0: (m0-3 x n0-1); stage A(t+1) half0 -> buf1 (A[buf1] last read prev ph6)
        ldB2(0, 0); ldA4(0, 0);
        stageAh(1, t + 1, 0);
        BARRIER(); quad(0, 0); BARRIER();

        // ph1: (m0-3 x n2-3); stage A(t+1) half1
        ldB2(0, 2);
        stageAh(1, t + 1, 1);
        BARRIER(); quad(0, 2); BARRIER();

        // ph2: (m4-7 x n0-1); stage B(t+2) half0 -> buf0 (B[buf0] consumed at ph1)
        ldA4(0, 4);
        if (s2) stageBh(0, t + 2, 0);
        BARRIER(); quad(4, 0); BARRIER();

        // ph3: (m4-7 x n2-3), no ds-reads; stage B(t+2) half1;
        // vmcnt(4): waits B(t+1)+A(t+1) landed, leaves B(t+2) in flight.
        if (s2) stageBh(0, t + 2, 1);
        BARRIER();
        quad(4, 2);
        if (s2) { VMCNT(4); } else { VMCNT(0); }
        BARRIER();

        // ---- tile t+1 (buf1) ----
        // ph4: (m0-3 x n0-1); stage A(t+2) half0 -> buf0 (A[buf0] consumed at ph2)
        ldB2(1, 0); ldA4(1, 0);
        if (s2) stageAh(0, t + 2, 0);
        BARRIER(); quad(0, 0); BARRIER();

        // ph5: (m0-3 x n2-3); stage A(t+2) half1
        ldB2(1, 2);
        if (s2) stageAh(0, t + 2, 1);
        BARRIER(); quad(0, 2); BARRIER();

        // ph6: (m4-7 x n0-1); stage B(t+3) half0 -> buf1 (B[buf1] consumed at ph5)
        ldA4(1, 4);
        if (s3) stageBh(1, t + 3, 0);
        BARRIER(); quad(4, 0); BARRIER();

        // ph7: (m4-7 x n2-3); stage B(t+3) half1;
        // vmcnt(4): waits B(t+2)+A(t+2) landed, leaves B(t+3) in flight.
        if (s3) stageBh(1, t + 3, 1);
        BARRIER();
        quad(4, 2);
        if (s3) { VMCNT(4); } else { VMCNT(0); }
        BARRIER();
    }

    // ---- C-write: layout col = lane&15, row = (lane>>4)*4 + reg (m89-verified)
    const int crb = (lane >> 4) * 4;
#pragma unroll
    for (int i = 0; i < 8; ++i)
#pragma unroll
        for (int j = 0; j < 4; ++j)
#pragma unroll
            for (int r = 0; r < 4; ++r) {
                const int rr = row0 + wm + i * 16 + crb + r;
                const int cc = col0 + wn + j * 16 + fr;
                out[(size_t)rr * D_OUTN + cc] = acc[i][j][r];
            }
}

// ---------- fallback (only if d_ws too small): naive fp32 ----------
__global__ __launch_bounds__(256) void naive_grouped(
    const float* __restrict__ A, const float* __restrict__ W,
    const int* __restrict__ offs_raw, float* __restrict__ out)
{
    const long long total = (long long)T_TOK * D_OUTN;
    long long idx = (long long)blockIdx.x * blockDim.x + threadIdx.x;
    const long long stride = (long long)gridDim.x * blockDim.x;
    const int ostride = (offs_raw[1] == 0) ? 2 : 1;
    for (; idx < total; idx += stride) {
        const int t = (int)(idx / D_OUTN);
        const int c = (int)(idx % D_OUTN);
        int g = 0;
        for (int i = 0; i < G_NUM - 1; ++i)
            if (t >= offs_raw[i * ostride]) g = i + 1;
        const float4* a4 = reinterpret_cast<const float4*>(A + (size_t)t * D_INK);
        const float4* w4 = reinterpret_cast<const float4*>(W + ((size_t)g * D_OUTN + c) * D_INK);
        float s = 0.f;
        for (int k = 0; k < D_INK / 4; ++k) {
            float4 av = a4[k], wv = w4[k];
            s += av.x * wv.x + av.y * wv.y + av.z * wv.z + av.w * wv.w;
        }
        out[idx] = s;
    }
}

extern "C" void kernel_launch(void* const* d_in, const int* in_sizes, int n_in,
                              void* d_out, int out_size, void* d_ws, size_t ws_size,
                              hipStream_t stream) {
    const float* hidden = (const float*)d_in[0];
    const int*   offs   = (const int*)d_in[1];
    const float* weight = (const float*)d_in[2];
    float* out = (float*)d_out;

    const size_t nA = (size_t)T_TOK * D_INK;            // 33.5M
    const size_t nW = (size_t)G_NUM * D_OUTN * D_INK;   // 134M
    const size_t need = (nA + nW) * sizeof(unsigned short);

    if (ws_size >= need) {
        unsigned short* Abf = (unsigned short*)d_ws;
        unsigned short* Wbf = Abf + nA;
        cvt_f32_bf16<<<2048, 256, 0, stream>>>(hidden, Abf, (long long)(nA / 8));
        cvt_f32_bf16<<<4096, 256, 0, stream>>>(weight, Wbf, (long long)(nW / 8));
        grouped_gemm_256<<<MT_TILES * NT_TILES, 512, 0, stream>>>(Abf, Wbf, offs, out);
    } else {
        naive_grouped<<<8192, 256, 0, stream>>>(hidden, weight, offs, out);
    }
}